// Round 3
// baseline (360.110 us; speedup 1.0000x reference)
//
#include <hip/hip_runtime.h>

// B=64, H=W=512, K=7, VALID conv -> 506x506.
#define HW    512
#define OW    506
#define TW    64     // output tile width (cols = lanes)
#define TH    64     // output tile height (4 row-groups of 16)
#define LSTR  72     // padded LDS row stride in floats (18 float4)
#define NF4   1280   // float4 slots staged (70 rows * 18 + pad -> 20480 B)

__global__ __launch_bounds__(256, 6) void conv7x7_v3(
    const float* __restrict__ in,      // [64][512][512]
    const float* __restrict__ weight,  // [7][7]
    const float* __restrict__ bias,    // [1]
    float* __restrict__ out)           // [64][506][506]
{
    __shared__ float tile[NF4 * 4];    // 20480 B -> 8 blocks/CU fit exactly

    const int tid = threadIdx.x;
    const int x0  = blockIdx.x * TW;
    const int y0  = blockIdx.y * TH;
    const int b   = blockIdx.z;
    const float* __restrict__ inb = in + (size_t)b * (HW * HW);

    // ---- weights + bias -> SGPRs (uniform across lanes) ----
    float wv[49];
#pragma unroll
    for (int i = 0; i < 49; ++i)
        wv[i] = __uint_as_float(__builtin_amdgcn_readfirstlane(__float_as_uint(weight[i])));
    const float bv = __uint_as_float(__builtin_amdgcn_readfirstlane(__float_as_uint(bias[0])));

    // ---- stage 70x72(padded) tile: async global->LDS, width 16, no VGPR cost ----
    // float4 p -> LDS byte 16p (linear, matches wave-uniform-base + lane*16).
    // Source: row r = p/18, col4 = p%18; clamp OOB to valid memory (garbage
    // lands only in pad cols / halo rows that guarded outputs never use).
#pragma unroll
    for (int k = 0; k < 5; ++k) {
        const int p  = k * 256 + tid;
        const int r  = p / 18;
        const int c4 = p - r * 18;
        const int gy = min(y0 + r, HW - 1);
        const int gx = min(x0 + 4 * c4, HW - 4);
        const float* src = inb + gy * HW + gx;
        __builtin_amdgcn_global_load_lds(
            (const __attribute__((address_space(1))) void*)src,
            (__attribute__((address_space(3))) void*)(tile + 4 * p),
            16, 0, 0);
    }
    __syncthreads();   // drains vmcnt before barrier

    // ---- compute: lane = output column, row-group of 16 outputs ----
    const int c     = tid & 63;
    const int g     = tid >> 6;
    const int rbase = 16 * g;
    const int cb    = c & ~1;          // 8B-aligned window base
    const bool odd  = (c & 1) != 0;

    float acc[16];
#pragma unroll
    for (int i = 0; i < 16; ++i) acc[i] = 0.f;

    const float* rowp = tile + rbase * LSTR + cb;

    // input rows rbase..rbase+21; each read once, feeds up to 7 outputs
#pragma unroll
    for (int ir = 0; ir < 22; ++ir) {
        const float2 a0 = *reinterpret_cast<const float2*>(rowp + ir * LSTR + 0);
        const float2 a1 = *reinterpret_cast<const float2*>(rowp + ir * LSTR + 2);
        const float2 a2 = *reinterpret_cast<const float2*>(rowp + ir * LSTR + 4);
        const float2 a3 = *reinterpret_cast<const float2*>(rowp + ir * LSTR + 6);
        const float f8[8] = {a0.x, a0.y, a1.x, a1.y, a2.x, a2.y, a3.x, a3.y};
        float wnd[7];
#pragma unroll
        for (int k2 = 0; k2 < 7; ++k2) wnd[k2] = odd ? f8[k2 + 1] : f8[k2];

#pragma unroll
        for (int kr = 0; kr < 7; ++kr) {
            const int s = ir - kr;            // compile-time after unroll
            if (s >= 0 && s < 16) {
#pragma unroll
                for (int kc = 0; kc < 7; ++kc)
                    acc[s] = fmaf(wv[kr * 7 + kc], wnd[kc], acc[s]);
            }
        }
    }

    // ---- store: 64 lanes = 64 consecutive floats per row (coalesced) ----
    const int ox = x0 + c;
    float* __restrict__ outb = out + (size_t)b * (OW * OW);
    if (ox < OW) {
#pragma unroll
        for (int s = 0; s < 16; ++s) {
            const int oy = y0 + rbase + s;
            if (oy < OW) outb[(size_t)oy * OW + ox] = acc[s] + bv;
        }
    }
}

extern "C" void kernel_launch(void* const* d_in, const int* in_sizes, int n_in,
                              void* d_out, int out_size, void* d_ws, size_t ws_size,
                              hipStream_t stream) {
    const float* enc_x  = (const float*)d_in[0];
    const float* weight = (const float*)d_in[1];
    const float* bias   = (const float*)d_in[2];
    float* outp         = (float*)d_out;

    dim3 grid(8, 8, 64);   // 8x8 tiles of 64x64 over 506x506, 64 images
    dim3 block(256);
    hipLaunchKernelGGL(conv7x7_v3, grid, block, 0, stream,
                       enc_x, weight, bias, outp);
}

// Round 4
// 202.615 us; speedup vs baseline: 1.7773x; 1.7773x over previous
//
#include <hip/hip_runtime.h>

// B=64, H=W=512, K=7, VALID conv -> 506x506.
#define HW    512
#define OW    506
#define TW    64      // output tile width  (cols = lanes)
#define TH    32      // output tile height (4 waves x 8 rows)
#define HR    38      // halo rows (32 + 6)
#define LSTR  72      // LDS row stride in floats (18 float4)
#define NF4   (HR*18) // 684 float4 staged per block (10944 B)

// ---- compile-time-forced unrolling: every acc/wv index is a template const,
// so nothing can be demoted to scratch (the v2/v3 failure mode). ----
template<int IR, int KR>
struct Scatter {
    static __device__ __forceinline__ void run(const float (&wnd)[7],
                                               const float (&wv)[49],
                                               float (&acc)[8]) {
        constexpr int S = IR - KR;
        if constexpr (S >= 0 && S < 8) {
#pragma unroll
            for (int kc = 0; kc < 7; ++kc)
                acc[S] = fmaf(wv[KR * 7 + kc], wnd[kc], acc[S]);
        }
        Scatter<IR, KR + 1>::run(wnd, wv, acc);
    }
};
template<int IR>
struct Scatter<IR, 7> {
    static __device__ __forceinline__ void run(const float (&)[7],
                                               const float (&)[49],
                                               float (&)[8]) {}
};

template<int IR>
struct Rows {
    static __device__ __forceinline__ void run(const float* rowp, bool odd,
                                               const float (&wv)[49],
                                               float (&acc)[8]) {
        // 8 floats of this input row (8B-aligned float2 reads; lane pairs
        // broadcast + 2 lanes/bank across the wave -> conflict-free, measured 0)
        const float2 a0 = *reinterpret_cast<const float2*>(rowp + IR * LSTR + 0);
        const float2 a1 = *reinterpret_cast<const float2*>(rowp + IR * LSTR + 2);
        const float2 a2 = *reinterpret_cast<const float2*>(rowp + IR * LSTR + 4);
        const float2 a3 = *reinterpret_cast<const float2*>(rowp + IR * LSTR + 6);
        const float f8[8] = {a0.x, a0.y, a1.x, a1.y, a2.x, a2.y, a3.x, a3.y};
        float wnd[7];
#pragma unroll
        for (int k = 0; k < 7; ++k) wnd[k] = odd ? f8[k + 1] : f8[k];
        Scatter<IR, 0>::run(wnd, wv, acc);
        Rows<IR + 1>::run(rowp, odd, wv, acc);
    }
};
template<>
struct Rows<14> {
    static __device__ __forceinline__ void run(const float*, bool,
                                               const float (&)[49],
                                               float (&)[8]) {}
};

__global__ __launch_bounds__(256, 6) void conv7x7_v4(
    const float* __restrict__ in,      // [64][512][512]
    const float* __restrict__ weight,  // [7][7]
    const float* __restrict__ bias,    // [1]
    float* __restrict__ out)           // [64][506][506]
{
    __shared__ float4 tile4[NF4];      // 10944 B -> many blocks/CU
    float* tile = reinterpret_cast<float*>(tile4);

    const int tid = threadIdx.x;
    const int x0  = blockIdx.x * TW;
    const int y0  = blockIdx.y * TH;
    const int b   = blockIdx.z;
    const float* __restrict__ inb = in + (size_t)b * (HW * HW);

    // ---- weights + bias -> SGPRs (uniform; const-indexed everywhere) ----
    float wv[49];
#pragma unroll
    for (int i = 0; i < 49; ++i)
        wv[i] = __uint_as_float(__builtin_amdgcn_readfirstlane(__float_as_uint(weight[i])));
    const float bv = __uint_as_float(__builtin_amdgcn_readfirstlane(__float_as_uint(bias[0])));

    // ---- stage 38x72 tile: per-lane float4 load -> ds_write_b128 ----
    // (plain VGPR path; v0 measured clean FETCH with this. Clamped sources:
    // garbage lands only in pad cols / halo rows that guarded stores never use.)
#pragma unroll
    for (int k = 0; k < 3; ++k) {
        const int p = tid + k * 256;
        if (p < NF4) {
            const int r  = p / 18;
            const int c4 = p - r * 18;
            const int gy = min(y0 + r, HW - 1);
            const int gx = min(x0 + 4 * c4, HW - 4);
            tile4[p] = *reinterpret_cast<const float4*>(inb + gy * HW + gx);
        }
    }
    __syncthreads();

    // ---- compute: lane = output column; wave g covers rows 8g..8g+7 ----
    const int c     = tid & 63;
    const int g     = tid >> 6;
    const int rbase = 8 * g;
    const int cb    = c & ~1;          // 8B-aligned window base
    const bool odd  = (c & 1) != 0;

    float acc[8];
#pragma unroll
    for (int i = 0; i < 8; ++i) acc[i] = 0.f;

    const float* rowp = tile + rbase * LSTR + cb;
    Rows<0>::run(rowp, odd, wv, acc);   // 14 input rows, each read once

    // ---- store: 64 lanes = 256B contiguous per row ----
    const int ox = x0 + c;
    float* __restrict__ outb = out + (size_t)b * (OW * OW);
    if (ox < OW) {
#pragma unroll
        for (int s = 0; s < 8; ++s) {
            const int oy = y0 + rbase + s;
            if (oy < OW) outb[(size_t)oy * OW + ox] = acc[s] + bv;
        }
    }
}

extern "C" void kernel_launch(void* const* d_in, const int* in_sizes, int n_in,
                              void* d_out, int out_size, void* d_ws, size_t ws_size,
                              hipStream_t stream) {
    const float* enc_x  = (const float*)d_in[0];
    const float* weight = (const float*)d_in[1];
    const float* bias   = (const float*)d_in[2];
    float* outp         = (float*)d_out;

    dim3 grid(8, 16, 64);   // 64-wide x 32-tall tiles over 506x506, 64 images
    dim3 block(256);
    hipLaunchKernelGGL(conv7x7_v4, grid, block, 0, stream,
                       enc_x, weight, bias, outp);
}

// Round 5
// 157.982 us; speedup vs baseline: 2.2794x; 1.2825x over previous
//
#include <hip/hip_runtime.h>

// B=64, H=W=512, K=7, VALID conv -> 506x506.
#define HW    512
#define OW    506
#define TW    64      // output tile width  (cols = lanes)
#define TH    32      // output tile height (4 waves x 8 rows)
#define HR    38      // halo rows (32 + 6)
#define LSTR  72      // LDS row stride in floats (18 float4)
#define NF4   (HR*18) // 684 float4 staged per block (10944 B)

// NOTE: 2nd launch_bounds arg = min waves/EU -> VGPR cap = 512/arg.
// (256,6) capped VGPRs at ~85 and forced a ~30-dword/thread spill in
// v3/v4 (FETCH/WRITE blew up 3-5x). Natural demand here ~110 (v0: 108).
// (256,4) -> cap 128: no spill, still 4 blocks/CU.
__global__ __launch_bounds__(256, 4) void conv7x7_v5(
    const float* __restrict__ in,      // [64][512][512]
    const float* __restrict__ weight,  // [7][7]
    const float* __restrict__ bias,    // [1]
    float* __restrict__ out)           // [64][506][506]
{
    __shared__ float4 tile4[NF4];      // 10944 B
    float* tile = reinterpret_cast<float*>(tile4);

    const int tid = threadIdx.x;
    const int x0  = blockIdx.x * TW;
    const int y0  = blockIdx.y * TH;
    const int b   = blockIdx.z;
    const float* __restrict__ inb = in + (size_t)b * (HW * HW);

    // ---- weights + bias -> uniform scalars (v0-proven pattern) ----
    float wv[49];
#pragma unroll
    for (int i = 0; i < 49; ++i)
        wv[i] = __uint_as_float(__builtin_amdgcn_readfirstlane(__float_as_uint(weight[i])));
    const float bv = __uint_as_float(__builtin_amdgcn_readfirstlane(__float_as_uint(bias[0])));

    // ---- stage 38x72 tile: per-lane float4 -> ds_write_b128 ----
    // Clamped sources: garbage lands only in pad cols / halo rows that
    // guarded stores never consume (verified tile-col/row usage bounds).
#pragma unroll
    for (int k = 0; k < 3; ++k) {
        const int p = tid + k * 256;
        if (p < NF4) {
            const int r  = p / 18;
            const int c4 = p - r * 18;
            const int gy = min(y0 + r, HW - 1);
            const int gx = min(x0 + 4 * c4, HW - 4);
            tile4[p] = *reinterpret_cast<const float4*>(inb + gy * HW + gx);
        }
    }
    __syncthreads();

    // ---- compute: lane = output column; wave g covers rows 8g..8g+7 ----
    // (this mapping measured 0 LDS bank conflicts in v2/v3/v4)
    const int c     = tid & 63;
    const int g     = tid >> 6;
    const int rbase = 8 * g;
    const int cb    = c & ~1;          // 8B-aligned window base
    const bool odd  = (c & 1) != 0;

    float acc[8];
#pragma unroll
    for (int i = 0; i < 8; ++i) acc[i] = 0.f;

    const float* rowp = tile + rbase * LSTR + cb;

    // 14 input rows, each read once; guarded scatter into 8 accumulators.
    // All indices compile-time after full unroll (v0-proven structure).
#pragma unroll
    for (int ir = 0; ir < 14; ++ir) {
        const float2 a0 = *reinterpret_cast<const float2*>(rowp + ir * LSTR + 0);
        const float2 a1 = *reinterpret_cast<const float2*>(rowp + ir * LSTR + 2);
        const float2 a2 = *reinterpret_cast<const float2*>(rowp + ir * LSTR + 4);
        const float2 a3 = *reinterpret_cast<const float2*>(rowp + ir * LSTR + 6);
        const float f8[8] = {a0.x, a0.y, a1.x, a1.y, a2.x, a2.y, a3.x, a3.y};
        float wnd[7];
#pragma unroll
        for (int k2 = 0; k2 < 7; ++k2) wnd[k2] = odd ? f8[k2 + 1] : f8[k2];

#pragma unroll
        for (int kr = 0; kr < 7; ++kr) {
            const int s = ir - kr;              // compile-time after unroll
            if (s >= 0 && s < 8) {
#pragma unroll
                for (int kc = 0; kc < 7; ++kc)
                    acc[s] = fmaf(wv[kr * 7 + kc], wnd[kc], acc[s]);
            }
        }
    }

    // ---- store: 64 lanes = 256B contiguous per row ----
    const int ox = x0 + c;
    float* __restrict__ outb = out + (size_t)b * (OW * OW);
    if (ox < OW) {
#pragma unroll
        for (int s = 0; s < 8; ++s) {
            const int oy = y0 + rbase + s;
            if (oy < OW) outb[(size_t)oy * OW + ox] = acc[s] + bv;
        }
    }
}

extern "C" void kernel_launch(void* const* d_in, const int* in_sizes, int n_in,
                              void* d_out, int out_size, void* d_ws, size_t ws_size,
                              hipStream_t stream) {
    const float* enc_x  = (const float*)d_in[0];
    const float* weight = (const float*)d_in[1];
    const float* bias   = (const float*)d_in[2];
    float* outp         = (float*)d_out;

    dim3 grid(8, 16, 64);   // 64-wide x 32-tall tiles over 506x506, 64 images
    dim3 block(256);
    hipLaunchKernelGGL(conv7x7_v5, grid, block, 0, stream,
                       enc_x, weight, bias, outp);
}

// Round 6
// 95.518 us; speedup vs baseline: 3.7701x; 1.6540x over previous
//
#include <hip/hip_runtime.h>

// B=64, H=W=512, K=7, VALID conv -> 506x506.
#define HW     512
#define OW     506
#define S      73          // LDS row stride in dwords: odd, ==1 mod 8 -> bank-free reads
#define TCOLS  64          // output cols per block
#define TROWS  96          // output rows per block (4 waves x 8 rowgroups x 3 rows)
#define IROWS  102         // input rows staged (96+6)
#define NDW    (IROWS * S) // 7446 dwords = 29.8 KB LDS

__global__ __launch_bounds__(256) void conv7x7_v6(
    const float* __restrict__ in,      // [64][512][512]
    const float* __restrict__ weight,  // [7][7]
    const float* __restrict__ bias,    // [1]
    float* __restrict__ out)           // [64][506][506]
{
    __shared__ float tile[NDW];

    const int tid = threadIdx.x;
    const int x0  = blockIdx.x * TCOLS;
    const int y0  = blockIdx.y * TROWS;
    const int b   = blockIdx.z;
    const float* __restrict__ inb = in + (size_t)b * (HW * HW);

    // ---- weights + bias -> SGPRs (uniform) ----
    float wv[49];
#pragma unroll
    for (int i = 0; i < 49; ++i)
        wv[i] = __uint_as_float(__builtin_amdgcn_readfirstlane(__float_as_uint(weight[i])));
    const float bv = __uint_as_float(__builtin_amdgcn_readfirstlane(__float_as_uint(bias[0])));

    // ---- stage 102 x 70 tile at stride 73 ----
    // ds_write_b32 at dword q = tid + 256k: consecutive dwords = 2 lanes/bank
    // (m136-verified free). Global side: 4B/lane, coalesced 256B/wave.
    // Pad cols 70..72 are never written and never read.
#pragma unroll
    for (int k = 0; k < 30; ++k) {
        const int q = tid + k * 256;
        if (q < NDW) {
            const int r = q / S;            // const divide -> magic mul
            const int c = q - r * S;
            if (c < 70) {
                const int gy = min(y0 + r, HW - 1);
                const int gx = min(x0 + c, HW - 1);
                tile[q] = inb[gy * HW + gx];
            }
        }
    }
    __syncthreads();

    // ---- thread -> 3x8 micro-tile ----
    // lane = (a<<3)|b8: bank over wave = (27a + 8b8) mod 32 -> each bank hit
    // by exactly 2 lanes with addresses 32 dwords apart = conflict-free.
    const int lane = tid & 63;
    const int w    = tid >> 6;
    const int a    = lane >> 3;            // row-group 0..7
    const int b8   = lane & 7;             // col-group 0..7
    const int r0   = w * 24 + a * 3;       // first output row (tile-local)
    const int cb   = 8 * b8;               // first output col (tile-local)

    float acc[24];
#pragma unroll
    for (int i = 0; i < 24; ++i) acc[i] = 0.f;

    const float* rp = tile + r0 * S + cb;

    // 9 input rows, each read once as 14 x ds_read_b32 (immediate offsets)
#pragma unroll
    for (int ir = 0; ir < 9; ++ir) {
        float win[14];
#pragma unroll
        for (int j = 0; j < 14; ++j) win[j] = rp[ir * S + j];

#pragma unroll
        for (int kr = 0; kr < 7; ++kr) {
            const int s = ir - kr;          // compile-time after unroll
            if (s >= 0 && s < 3) {
#pragma unroll
                for (int kc = 0; kc < 7; ++kc) {
                    const float wk = wv[kr * 7 + kc];
#pragma unroll
                    for (int j = 0; j < 8; ++j)
                        acc[s * 8 + j] = fmaf(wk, win[kc + j], acc[s * 8 + j]);
                }
            }
        }
    }

    // ---- store 3 rows x 8 cols as float2 pairs (always fully valid or fully OOB) ----
    const int ox0 = x0 + cb;
    float* __restrict__ outb = out + (size_t)b * (OW * OW);
#pragma unroll
    for (int s = 0; s < 3; ++s) {
        const int oy = y0 + r0 + s;
        if (oy < OW) {
            float* orow = outb + (size_t)oy * OW + ox0;
#pragma unroll
            for (int p = 0; p < 4; ++p) {
                if (ox0 + 2 * p < OW) {    // ox0 even, OW even -> pair never straddles
                    *reinterpret_cast<float2*>(orow + 2 * p) =
                        make_float2(acc[s * 8 + 2 * p] + bv, acc[s * 8 + 2 * p + 1] + bv);
                }
            }
        }
    }
}

extern "C" void kernel_launch(void* const* d_in, const int* in_sizes, int n_in,
                              void* d_out, int out_size, void* d_ws, size_t ws_size,
                              hipStream_t stream) {
    const float* enc_x  = (const float*)d_in[0];
    const float* weight = (const float*)d_in[1];
    const float* bias   = (const float*)d_in[2];
    float* outp         = (float*)d_out;

    dim3 grid(8, 6, 64);    // 8x64 cols, 6x96 rows (covers 506), 64 images
    dim3 block(256);
    hipLaunchKernelGGL(conv7x7_v6, grid, block, 0, stream,
                       enc_x, weight, bias, outp);
}